// Round 15
// baseline (160.970 us; speedup 1.0000x reference)
//
#include <hip/hip_runtime.h>
#include <hip/hip_bf16.h>
#include <hip/hip_cooperative_groups.h>

namespace cg = cooperative_groups;

#define DIM   2048
#define NEXP  64
#define NTOK  32768
#define KC    32               // k-floats per chunk = one MFMA k-step
#define NC    64               // chunks
#define TB    64               // tokens per block (4 waves x 16)
#define NBLK  (NTOK / TB)      // 512 blocks = 2/CU (co-resident, cooperative)
#define NSLOT 5                // B slots (stage 4 ahead; (c+4)%5 barrier-safe)
#define BB    12288            // B bytes per chunk (12 frags x 64 lanes x 16B)
#define WFOFF 1024             // byte offset of w-fragments inside d_ws

typedef __attribute__((ext_vector_type(8))) short bf16x8;
typedef __attribute__((ext_vector_type(4))) float f32x4;

typedef __attribute__((address_space(1))) const void gvoid_t;
typedef __attribute__((address_space(3))) void lvoid_t;
#define GLDS16(g, l) __builtin_amdgcn_global_load_lds((gvoid_t*)(g), (lvoid_t*)(l), 16, 0, 0)

// RNE fp32 -> bf16; returns fp32 value of the bf16 (splits are exact diffs)
__device__ __forceinline__ float rne_split(float v, short& h) {
    __hip_bfloat16 hb = __float2bfloat16(v);
    h = __builtin_bit_cast(short, hb);
    return __bfloat162float(hb);
}

__device__ __forceinline__ void split8(const float4& a, const float4& b,
                                       bf16x8& H, bf16x8& M, bf16x8& L) {
    const float vs[8] = {a.x, a.y, a.z, a.w, b.x, b.y, b.z, b.w};
#pragma unroll
    for (int j = 0; j < 8; ++j) {
        short h, m, l;
        const float fh = rne_split(vs[j], h);
        const float e1 = vs[j] - fh;            // exact
        const float fm = rne_split(e1, m);
        const float e2 = e1 - fm;               // exact
        rne_split(e2, l);
        H[j] = h; M[j] = m; L[j] = l;
    }
}

// Pre-split w into CHUNK-MAJOR fragment order (12 KB/chunk); also zero denom.
// unit idx = ((ks*3 + lvl)*4 + ni)*64 + lane covers
// B[k = ks*32 + 8*(lane>>4) + j][n = ni*16 + (lane&15)].
__global__ __launch_bounds__(256)
void wsplit_kernel(const float* __restrict__ w, bf16x8* __restrict__ wf,
                   float* __restrict__ denom) {
    if (blockIdx.x == 0 && threadIdx.x < NEXP) denom[threadIdx.x] = 0.0f;
    const int tid  = blockIdx.x * 256 + threadIdx.x;   // 16384 threads
    const int lane = tid & 63;
    const int ni   = (tid >> 6) & 3;
    const int ks   = tid >> 8;
    const int n    = ni * 16 + (lane & 15);
    const int k0   = ks * KC + (lane >> 4) * 8;
    bf16x8 H, M, L;
#pragma unroll
    for (int j = 0; j < 8; ++j) {
        const float v = w[(size_t)(k0 + j) * NEXP + n];
        short h, m, l;
        const float fh = rne_split(v, h);
        const float e1 = v - fh;
        const float fm = rne_split(e1, m);
        rne_split(e1 - fm, l);
        H[j] = h; M[j] = m; L[j] = l;
    }
    wf[((size_t)(ks * 3 + 0) * 4 + ni) * 64 + lane] = H;
    wf[((size_t)(ks * 3 + 1) * 4 + ni) * 64 + lane] = M;
    wf[((size_t)(ks * 3 + 2) * 4 + ni) * 64 + lane] = L;
}

__global__ __launch_bounds__(256, 2)
void gate_kernel(const float* __restrict__ x, const bf16x8* __restrict__ wf,
                 const float* __restrict__ b, float* __restrict__ out,
                 float* __restrict__ denom)
{
    __shared__ __align__(16) char slab[NSLOT * BB];   // 60 KB -> 2 blocks/CU
    __shared__ float dlds[NEXP];

    const int tid  = threadIdx.x;
    const int lane = tid & 63;
    const int l15  = lane & 15;
    const int l4   = lane >> 4;
    const int wv   = tid >> 6;
    const int tok0 = blockIdx.x * TB;

    if (tid < NEXP) dlds[tid] = 0.0f;

    float bias[4];
#pragma unroll
    for (int ni = 0; ni < 4; ++ni) bias[ni] = b[ni * 16 + l15];

    // A-side: lane's fragment k-range is its own contiguous 32B of row
    // tok0 + wv*16 + l15 (one 16-token m-tile per wave)
    const float* xr0 = x + (size_t)(tok0 + wv * 16 + l15) * DIM + l4 * 8;

// x loads for chunk c -> 2 float4 regs (direct to VGPR, 2-deep ping-pong)
#define LOADX(X, c) {                                                  \
    X[0] = *(const float4*)(xr0 + (size_t)(c) * KC);                   \
    X[1] = *(const float4*)(xr0 + (size_t)(c) * KC + 4); }

// cooperative B stage: 256 threads x 3 x 16B = 12 KB, linear dest
#define STAGE(slot, c) {                                               \
    const char* _src = (const char*)wf + (size_t)(c) * BB + tid * 16;  \
    char* _dst = slab + (size_t)(slot) * BB + tid * 16;                \
    GLDS16(_src, _dst);                                                \
    GLDS16(_src + 4096, _dst + 4096);                                  \
    GLDS16(_src + 8192, _dst + 8192); }

    f32x4 acc[4];
#pragma unroll
    for (int ni = 0; ni < 4; ++ni) acc[ni] = (f32x4){0.f, 0.f, 0.f, 0.f};

    float4 xa[2], xb[2];
    // prologue, order pinned for vmcnt math:
    // chronological queue entering iter 0: B0(3),B1(3),x0(2),B2(3),x1(2),B3(3) = 16
    STAGE(0, 0)
    __builtin_amdgcn_sched_barrier(0);
    STAGE(1, 1)
    __builtin_amdgcn_sched_barrier(0);
    LOADX(xa, 0)
    __builtin_amdgcn_sched_barrier(0);
    STAGE(2, 2)
    __builtin_amdgcn_sched_barrier(0);
    LOADX(xb, 1)
    __builtin_amdgcn_sched_barrier(0);
    STAGE(3, 3)
    __builtin_amdgcn_sched_barrier(0);

// one chunk: wait {..,B(c),x(c)} -> barrier -> read frags -> split XC (consume)
// -> reload XC with x(c+2) -> stage B(c+4) -> 24 MFMA.
// vmcnt(8) leaves exactly {B(c+2), x(c+1), B(c+3)} = 8 ops in flight.
#define ITER(c, scomp, sstage, XC) {                                   \
    asm volatile("s_waitcnt vmcnt(8)" ::: "memory");                   \
    __builtin_amdgcn_s_barrier();                                      \
    __builtin_amdgcn_sched_barrier(0);                                 \
    const bf16x8* _bl = (const bf16x8*)(slab + (size_t)(scomp) * BB);  \
    bf16x8 Bf[12];                                                     \
    _Pragma("unroll")                                                  \
    for (int _f = 0; _f < 12; ++_f) Bf[_f] = _bl[_f * 64 + lane];      \
    __builtin_amdgcn_sched_barrier(0);                                 \
    bf16x8 Ah, Am, Al;                                                 \
    split8(XC[0], XC[1], Ah, Am, Al);                                  \
    __builtin_amdgcn_sched_barrier(0);                                 \
    { const int _cx = ((c) + 2 < NC) ? (c) + 2 : NC - 1;               \
      LOADX(XC, _cx) }                                                 \
    __builtin_amdgcn_sched_barrier(0);                                 \
    { const int _cs = ((c) + 4 < NC) ? (c) + 4 : NC - 1;               \
      STAGE(sstage, _cs) }                                             \
    __builtin_amdgcn_sched_barrier(0);                                 \
    _Pragma("unroll")                                                  \
    for (int _ni = 0; _ni < 4; ++_ni) {                                \
        f32x4 _a = acc[_ni];                                           \
        _a = __builtin_amdgcn_mfma_f32_16x16x32_bf16(Ah, Bf[_ni],     _a, 0, 0, 0); \
        _a = __builtin_amdgcn_mfma_f32_16x16x32_bf16(Ah, Bf[4 + _ni], _a, 0, 0, 0); \
        _a = __builtin_amdgcn_mfma_f32_16x16x32_bf16(Am, Bf[_ni],     _a, 0, 0, 0); \
        _a = __builtin_amdgcn_mfma_f32_16x16x32_bf16(Ah, Bf[8 + _ni], _a, 0, 0, 0); \
        _a = __builtin_amdgcn_mfma_f32_16x16x32_bf16(Am, Bf[4 + _ni], _a, 0, 0, 0); \
        _a = __builtin_amdgcn_mfma_f32_16x16x32_bf16(Al, Bf[_ni],     _a, 0, 0, 0); \
        acc[_ni] = _a;                                                 \
    } }

    int scomp = 0, sstage = 4;
#pragma unroll 1
    for (int c = 0; c < NC; c += 2) {
        ITER(c, scomp, sstage, xa)
        if (++scomp == NSLOT) scomp = 0;
        if (++sstage == NSLOT) sstage = 0;
        ITER(c + 1, scomp, sstage, xb)
        if (++scomp == NSLOT) scomp = 0;
        if (++sstage == NSLOT) sstage = 0;
    }

    asm volatile("s_waitcnt vmcnt(0)" ::: "memory");   // drain tail dummies
    __syncthreads();   // dlds zero visible; slab dead

    // ---- epilogue part 1: softmax/argmax in registers; block denom in LDS
    float gv[4]; int lev[4];
#pragma unroll
    for (int r = 0; r < 4; ++r) {
        const float v0 = acc[0][r] + bias[0];
        const float v1 = acc[1][r] + bias[1];
        const float v2 = acc[2][r] + bias[2];
        const float v3 = acc[3][r] + bias[3];

        // lane-local argmax (ascending e => first-index ties)
        float lm = v0; int le = l15;
        if (v1 > lm) { lm = v1; le = l15 + 16; }
        if (v2 > lm) { lm = v2; le = l15 + 32; }
        if (v3 > lm) { lm = v3; le = l15 + 48; }
#pragma unroll
        for (int off = 1; off < 16; off <<= 1) {
            const float om = __shfl_xor(lm, off);
            const int   oe = __shfl_xor(le, off);
            if (om > lm || (om == lm && oe < le)) { lm = om; le = oe; }
        }
        float s = __expf(v0 - lm) + __expf(v1 - lm) +
                  __expf(v2 - lm) + __expf(v3 - lm);
#pragma unroll
        for (int off = 1; off < 16; off <<= 1) s += __shfl_xor(s, off);
        gv[r]  = 1.0f / s;            // top-1 gate = exp(0)/sum
        lev[r] = le;
        if (l15 == 0) atomicAdd(&dlds[le], gv[r]);
    }

    __syncthreads();
    if (tid < NEXP) atomicAdd(&denom[tid], dlds[tid]);

    // ---- grid-wide barrier: denom complete; then scale + single out write
    cg::this_grid().sync();

    const float sc0 = (float)NTOK / (denom[l15]      + 1e-6f);
    const float sc1 = (float)NTOK / (denom[l15 + 16] + 1e-6f);
    const float sc2 = (float)NTOK / (denom[l15 + 32] + 1e-6f);
    const float sc3 = (float)NTOK / (denom[l15 + 48] + 1e-6f);

#pragma unroll
    for (int r = 0; r < 4; ++r) {
        const int t = tok0 + wv * 16 + 4 * l4 + r;
        float* orow = out + (size_t)t * NEXP + l15;
        orow[0]  = (lev[r] == l15     ) ? gv[r] * sc0 : 0.0f;
        orow[16] = (lev[r] == l15 + 16) ? gv[r] * sc1 : 0.0f;
        orow[32] = (lev[r] == l15 + 32) ? gv[r] * sc2 : 0.0f;
        orow[48] = (lev[r] == l15 + 48) ? gv[r] * sc3 : 0.0f;
    }
}

extern "C" void kernel_launch(void* const* d_in, const int* in_sizes, int n_in,
                              void* d_out, int out_size, void* d_ws, size_t ws_size,
                              hipStream_t stream) {
    const float* x = (const float*)d_in[0];
    const float* w = (const float*)d_in[1];
    const float* b = (const float*)d_in[2];
    float*  out   = (float*)d_out;
    float*  denom = (float*)d_ws;                               // 64 floats
    bf16x8* wf    = (bf16x8*)((char*)d_ws + WFOFF);             // 768 KB frags

    wsplit_kernel<<<64, 256, 0, stream>>>(w, wf, denom);        // also zeroes denom

    void* args[] = {(void*)&x, (void*)&wf, (void*)&b, (void*)&out, (void*)&denom};
    hipLaunchCooperativeKernel((void*)gate_kernel, dim3(NBLK), dim3(256),
                               args, 0, stream);
}

// Round 16
// 80.166 us; speedup vs baseline: 2.0079x; 2.0079x over previous
//
#include <hip/hip_runtime.h>
#include <hip/hip_bf16.h>

#define DIM   2048
#define NEXP  64
#define NTOK  32768
#define KC    32               // k-floats per chunk = one MFMA k-step
#define NC    64               // chunks
#define TB    64               // tokens per block (4 waves x 16)
#define NBLK  (NTOK / TB)      // 512 blocks = 2/CU
#define NSLOT 5                // B slots (stage 4 ahead; (c+4)%5 barrier-safe)
#define BB    12288            // B bytes per chunk (12 frags x 64 lanes x 16B)
#define WFOFF 1024             // byte offset of w-fragments inside d_ws

typedef __attribute__((ext_vector_type(8))) short bf16x8;
typedef __attribute__((ext_vector_type(4))) float f32x4;

typedef __attribute__((address_space(1))) const void gvoid_t;
typedef __attribute__((address_space(3))) void lvoid_t;
#define GLDS16(g, l) __builtin_amdgcn_global_load_lds((gvoid_t*)(g), (lvoid_t*)(l), 16, 0, 0)

// RNE fp32 -> bf16; returns fp32 value of the bf16 (splits are exact diffs)
__device__ __forceinline__ float rne_split(float v, short& h) {
    __hip_bfloat16 hb = __float2bfloat16(v);
    h = __builtin_bit_cast(short, hb);
    return __bfloat162float(hb);
}

__device__ __forceinline__ void split8(const float4& a, const float4& b,
                                       bf16x8& H, bf16x8& M, bf16x8& L) {
    const float vs[8] = {a.x, a.y, a.z, a.w, b.x, b.y, b.z, b.w};
#pragma unroll
    for (int j = 0; j < 8; ++j) {
        short h, m, l;
        const float fh = rne_split(vs[j], h);
        const float e1 = vs[j] - fh;            // exact
        const float fm = rne_split(e1, m);
        const float e2 = e1 - fm;               // exact
        rne_split(e2, l);
        H[j] = h; M[j] = m; L[j] = l;
    }
}

// Pre-split w into CHUNK-MAJOR fragment order (12 KB/chunk); also zero denom.
// unit idx = ((ks*3 + lvl)*4 + ni)*64 + lane covers
// B[k = ks*32 + 8*(lane>>4) + j][n = ni*16 + (lane&15)].
__global__ __launch_bounds__(256)
void wsplit_kernel(const float* __restrict__ w, bf16x8* __restrict__ wf,
                   float* __restrict__ denom) {
    if (blockIdx.x == 0 && threadIdx.x < NEXP) denom[threadIdx.x] = 0.0f;
    const int tid  = blockIdx.x * 256 + threadIdx.x;   // 16384 threads
    const int lane = tid & 63;
    const int ni   = (tid >> 6) & 3;
    const int ks   = tid >> 8;
    const int n    = ni * 16 + (lane & 15);
    const int k0   = ks * KC + (lane >> 4) * 8;
    bf16x8 H, M, L;
#pragma unroll
    for (int j = 0; j < 8; ++j) {
        const float v = w[(size_t)(k0 + j) * NEXP + n];
        short h, m, l;
        const float fh = rne_split(v, h);
        const float e1 = v - fh;
        const float fm = rne_split(e1, m);
        rne_split(e1 - fm, l);
        H[j] = h; M[j] = m; L[j] = l;
    }
    wf[((size_t)(ks * 3 + 0) * 4 + ni) * 64 + lane] = H;
    wf[((size_t)(ks * 3 + 1) * 4 + ni) * 64 + lane] = M;
    wf[((size_t)(ks * 3 + 2) * 4 + ni) * 64 + lane] = L;
}

__global__ __launch_bounds__(256, 2)
void gate_kernel(const float* __restrict__ x, const bf16x8* __restrict__ wf,
                 const float* __restrict__ b, float* __restrict__ out,
                 float* __restrict__ denom)
{
    __shared__ __align__(16) char slab[NSLOT * BB];   // 60 KB -> 2 blocks/CU
    __shared__ float dlds[NEXP];

    const int tid  = threadIdx.x;
    const int lane = tid & 63;
    const int l15  = lane & 15;
    const int l4   = lane >> 4;
    const int wv   = tid >> 6;
    const int tok0 = blockIdx.x * TB;

    if (tid < NEXP) dlds[tid] = 0.0f;

    float bias[4];
#pragma unroll
    for (int ni = 0; ni < 4; ++ni) bias[ni] = b[ni * 16 + l15];

    // A-side: lane's fragment k-range is its own contiguous 32B of row
    // tok0 + wv*16 + l15 (one 16-token m-tile per wave)
    const float* xr0 = x + (size_t)(tok0 + wv * 16 + l15) * DIM + l4 * 8;

// x loads for chunk c -> 2 float4 regs (direct to VGPR, 2-deep ping-pong)
#define LOADX(X, c) {                                                  \
    X[0] = *(const float4*)(xr0 + (size_t)(c) * KC);                   \
    X[1] = *(const float4*)(xr0 + (size_t)(c) * KC + 4); }

// cooperative B stage: 256 threads x 3 x 16B = 12 KB, linear dest
#define STAGE(slot, c) {                                               \
    const char* _src = (const char*)wf + (size_t)(c) * BB + tid * 16;  \
    char* _dst = slab + (size_t)(slot) * BB + tid * 16;                \
    GLDS16(_src, _dst);                                                \
    GLDS16(_src + 4096, _dst + 4096);                                  \
    GLDS16(_src + 8192, _dst + 8192); }

    f32x4 acc[4];
#pragma unroll
    for (int ni = 0; ni < 4; ++ni) acc[ni] = (f32x4){0.f, 0.f, 0.f, 0.f};

    float4 xa[2], xb[2];
    // prologue, order pinned for vmcnt math:
    // chronological queue entering iter 0: B0(3),B1(3),x0(2),B2(3),x1(2),B3(3) = 16
    STAGE(0, 0)
    __builtin_amdgcn_sched_barrier(0);
    STAGE(1, 1)
    __builtin_amdgcn_sched_barrier(0);
    LOADX(xa, 0)
    __builtin_amdgcn_sched_barrier(0);
    STAGE(2, 2)
    __builtin_amdgcn_sched_barrier(0);
    LOADX(xb, 1)
    __builtin_amdgcn_sched_barrier(0);
    STAGE(3, 3)
    __builtin_amdgcn_sched_barrier(0);

// one chunk: wait {..,B(c),x(c)} -> barrier -> read frags -> split XC (consume)
// -> reload XC with x(c+2) -> stage B(c+4) -> 24 MFMA.
// vmcnt(8) leaves exactly {B(c+2), x(c+1), B(c+3)} = 8 ops in flight.
#define ITER(c, scomp, sstage, XC) {                                   \
    asm volatile("s_waitcnt vmcnt(8)" ::: "memory");                   \
    __builtin_amdgcn_s_barrier();                                      \
    __builtin_amdgcn_sched_barrier(0);                                 \
    const bf16x8* _bl = (const bf16x8*)(slab + (size_t)(scomp) * BB);  \
    bf16x8 Bf[12];                                                     \
    _Pragma("unroll")                                                  \
    for (int _f = 0; _f < 12; ++_f) Bf[_f] = _bl[_f * 64 + lane];      \
    __builtin_amdgcn_sched_barrier(0);                                 \
    bf16x8 Ah, Am, Al;                                                 \
    split8(XC[0], XC[1], Ah, Am, Al);                                  \
    __builtin_amdgcn_sched_barrier(0);                                 \
    { const int _cx = ((c) + 2 < NC) ? (c) + 2 : NC - 1;               \
      LOADX(XC, _cx) }                                                 \
    __builtin_amdgcn_sched_barrier(0);                                 \
    { const int _cs = ((c) + 4 < NC) ? (c) + 4 : NC - 1;               \
      STAGE(sstage, _cs) }                                             \
    __builtin_amdgcn_sched_barrier(0);                                 \
    _Pragma("unroll")                                                  \
    for (int _ni = 0; _ni < 4; ++_ni) {                                \
        f32x4 _a = acc[_ni];                                           \
        _a = __builtin_amdgcn_mfma_f32_16x16x32_bf16(Ah, Bf[_ni],     _a, 0, 0, 0); \
        _a = __builtin_amdgcn_mfma_f32_16x16x32_bf16(Ah, Bf[4 + _ni], _a, 0, 0, 0); \
        _a = __builtin_amdgcn_mfma_f32_16x16x32_bf16(Am, Bf[_ni],     _a, 0, 0, 0); \
        _a = __builtin_amdgcn_mfma_f32_16x16x32_bf16(Ah, Bf[8 + _ni], _a, 0, 0, 0); \
        _a = __builtin_amdgcn_mfma_f32_16x16x32_bf16(Am, Bf[4 + _ni], _a, 0, 0, 0); \
        _a = __builtin_amdgcn_mfma_f32_16x16x32_bf16(Al, Bf[_ni],     _a, 0, 0, 0); \
        acc[_ni] = _a;                                                 \
    } }

    int scomp = 0, sstage = 4;
#pragma unroll 1
    for (int c = 0; c < NC; c += 2) {
        ITER(c, scomp, sstage, xa)
        if (++scomp == NSLOT) scomp = 0;
        if (++sstage == NSLOT) sstage = 0;
        ITER(c + 1, scomp, sstage, xb)
        if (++scomp == NSLOT) scomp = 0;
        if (++sstage == NSLOT) sstage = 0;
    }

    asm volatile("s_waitcnt vmcnt(0)" ::: "memory");   // drain tail dummies
    __syncthreads();   // dlds zero visible; slab dead

    // epilogue (verified): token t = tok0 + wv*16 + 4*l4 + r, expert e = ni*16+l15
#pragma unroll
    for (int r = 0; r < 4; ++r) {
        const float v0 = acc[0][r] + bias[0];
        const float v1 = acc[1][r] + bias[1];
        const float v2 = acc[2][r] + bias[2];
        const float v3 = acc[3][r] + bias[3];

        // lane-local argmax (ascending e => first-index ties)
        float lm = v0; int le = l15;
        if (v1 > lm) { lm = v1; le = l15 + 16; }
        if (v2 > lm) { lm = v2; le = l15 + 32; }
        if (v3 > lm) { lm = v3; le = l15 + 48; }
#pragma unroll
        for (int off = 1; off < 16; off <<= 1) {
            const float om = __shfl_xor(lm, off);
            const int   oe = __shfl_xor(le, off);
            if (om > lm || (om == lm && oe < le)) { lm = om; le = oe; }
        }
        float s = __expf(v0 - lm) + __expf(v1 - lm) +
                  __expf(v2 - lm) + __expf(v3 - lm);
#pragma unroll
        for (int off = 1; off < 16; off <<= 1) s += __shfl_xor(s, off);
        const float g = 1.0f / s;            // top-1 gate = exp(0)/sum

        const int t = tok0 + wv * 16 + 4 * l4 + r;
        float* orow = out + (size_t)t * NEXP + l15;
        orow[0]  = (le == l15     ) ? g : 0.0f;
        orow[16] = (le == l15 + 16) ? g : 0.0f;
        orow[32] = (le == l15 + 32) ? g : 0.0f;
        orow[48] = (le == l15 + 48) ? g : 0.0f;
        if (l15 == 0) atomicAdd(&dlds[le], g);
    }

    __syncthreads();
    if (tid < NEXP) atomicAdd(&denom[tid], dlds[tid]);
}

// out[n,e] *= capacity / (denom[e] + eps); zeros stay zero (branch-free)
__global__ __launch_bounds__(256)
void scale_kernel(float* __restrict__ out, const float* __restrict__ denom)
{
    __shared__ float sc[NEXP];
    if (threadIdx.x < NEXP)
        sc[threadIdx.x] = (float)NTOK / (denom[threadIdx.x] + 1e-6f);
    __syncthreads();

    const size_t i = (size_t)blockIdx.x * blockDim.x + threadIdx.x; // float4 idx
    float4 v = ((const float4*)out)[i];
    const int e0 = (int)((i * 4) & (NEXP - 1));
    v.x *= sc[e0]; v.y *= sc[e0 + 1]; v.z *= sc[e0 + 2]; v.w *= sc[e0 + 3];
    ((float4*)out)[i] = v;
}

extern "C" void kernel_launch(void* const* d_in, const int* in_sizes, int n_in,
                              void* d_out, int out_size, void* d_ws, size_t ws_size,
                              hipStream_t stream) {
    const float* x = (const float*)d_in[0];
    const float* w = (const float*)d_in[1];
    const float* b = (const float*)d_in[2];
    float*  out   = (float*)d_out;
    float*  denom = (float*)d_ws;                               // 64 floats
    bf16x8* wf    = (bf16x8*)((char*)d_ws + WFOFF);             // 768 KB frags

    wsplit_kernel<<<64, 256, 0, stream>>>(w, wf, denom);        // also zeroes denom
    gate_kernel<<<NBLK, 256, 0, stream>>>(x, wf, b, out, denom);
    scale_kernel<<<(NTOK * NEXP / 4) / 256, 256, 0, stream>>>(out, denom);
}